// Round 5
// baseline (481.685 us; speedup 1.0000x reference)
//
#include <hip/hip_runtime.h>
#include <hip/hip_bf16.h>
#include <math.h>

#define AS1 __attribute__((address_space(1)))
#define AS3 __attribute__((address_space(3)))

typedef __bf16  bf16x8 __attribute__((ext_vector_type(8)));
typedef float   f32x4  __attribute__((ext_vector_type(4)));
typedef __hip_bfloat16 bf16;

__device__ __forceinline__ void gload_lds16(const void* g, void* l) {
  __builtin_amdgcn_global_load_lds((const AS1 void*)g, (AS3 void*)l, 16, 0, 0);
}

// ---------------- weight conversion f32 -> bf16 ----------------
__global__ __launch_bounds__(256) void k_conv_weights(
    const float* __restrict__ qkvw, const float* __restrict__ projw,
    const float* __restrict__ w1, const float* __restrict__ w2,
    bf16* __restrict__ dst)
{
  int i = blockIdx.x * 256 + threadIdx.x;   // grid covers exactly 786432
  float v;
  if (i < 196608)       v = qkvw[i];
  else if (i < 262144)  v = projw[i - 196608];
  else if (i < 524288)  v = w1[i - 262144];
  else                  v = w2[i - 524288];
  dst[i] = __float2bfloat16(v);
}

// ---------------- rel-pos bias table: btab[h][n][m] ----------------
__global__ __launch_bounds__(256) void k_build_btab(
    const float* __restrict__ rel_bias, float* __restrict__ btab)
{
  int i = blockIdx.x * 256 + threadIdx.x;   // 32768
  int h = i >> 12, r = i & 4095, n = r >> 6, m = r & 63;
  int idx = ((n >> 3) - (m >> 3) + 7) * 15 + ((n & 7) - (m & 7) + 7);
  btab[i] = rel_bias[idx * 8 + h];
}

// ---------------- LN1 + roll(-4,-4) + window partition, f32 -> bf16 ----------------
__global__ __launch_bounds__(256) void k_ln1_window(
    const float* __restrict__ x, const float* __restrict__ sc,
    const float* __restrict__ bi, bf16* __restrict__ hout)
{
  int t = blockIdx.x * 4 + (threadIdx.x >> 6);
  int lane = threadIdx.x & 63;
  int win = t >> 6, nn = t & 63;
  int b = win >> 6, ww = win & 63;
  int ry = ((ww >> 3) << 3) + (nn >> 3);
  int rx = ((ww & 7) << 3) + (nn & 7);
  int sy = (ry + 4) & 63, sx = (rx + 4) & 63;
  const float* src = x + ((size_t)(((b << 6) + sy) << 6) + sx) * 256;
  f32x4 v = *(const f32x4*)(src + lane * 4);
  float s = v[0] + v[1] + v[2] + v[3];
  #pragma unroll
  for (int o = 1; o < 64; o <<= 1) s += __shfl_xor(s, o);
  float mu = s * (1.0f / 256.0f);
  float d0 = v[0]-mu, d1 = v[1]-mu, d2 = v[2]-mu, d3 = v[3]-mu;
  float q = d0*d0 + d1*d1 + d2*d2 + d3*d3;
  #pragma unroll
  for (int o = 1; o < 64; o <<= 1) q += __shfl_xor(q, o);
  float rstd = rsqrtf(q * (1.0f / 256.0f) + 1e-5f);
  int c = lane * 4;
  union { bf16 h[4]; uint2 u; } pk;
  pk.h[0] = __float2bfloat16(d0 * rstd * sc[c+0] + bi[c+0]);
  pk.h[1] = __float2bfloat16(d1 * rstd * sc[c+1] + bi[c+1]);
  pk.h[2] = __float2bfloat16(d2 * rstd * sc[c+2] + bi[c+2]);
  pk.h[3] = __float2bfloat16(d3 * rstd * sc[c+3] + bi[c+3]);
  *(uint2*)(hout + (size_t)t * 256 + c) = pk.u;
}

// ---------------- LN2 (pixel-major), f32 -> bf16 ----------------
__global__ __launch_bounds__(256) void k_ln2(
    const float* __restrict__ x1, const float* __restrict__ sc,
    const float* __restrict__ bi, bf16* __restrict__ out)
{
  int t = blockIdx.x * 4 + (threadIdx.x >> 6);
  int lane = threadIdx.x & 63;
  const float* src = x1 + (size_t)t * 256;
  f32x4 v = *(const f32x4*)(src + lane * 4);
  float s = v[0] + v[1] + v[2] + v[3];
  #pragma unroll
  for (int o = 1; o < 64; o <<= 1) s += __shfl_xor(s, o);
  float mu = s * (1.0f / 256.0f);
  float d0 = v[0]-mu, d1 = v[1]-mu, d2 = v[2]-mu, d3 = v[3]-mu;
  float q = d0*d0 + d1*d1 + d2*d2 + d3*d3;
  #pragma unroll
  for (int o = 1; o < 64; o <<= 1) q += __shfl_xor(q, o);
  float rstd = rsqrtf(q * (1.0f / 256.0f) + 1e-5f);
  int c = lane * 4;
  union { bf16 h[4]; uint2 u; } pk;
  pk.h[0] = __float2bfloat16(d0 * rstd * sc[c+0] + bi[c+0]);
  pk.h[1] = __float2bfloat16(d1 * rstd * sc[c+1] + bi[c+1]);
  pk.h[2] = __float2bfloat16(d2 * rstd * sc[c+2] + bi[c+2]);
  pk.h[3] = __float2bfloat16(d3 * rstd * sc[c+3] + bi[c+3]);
  *(uint2*)(out + (size_t)t * 256 + c) = pk.u;
}

// ============ register-resident GEMM (K=256), no LDS, no barriers ============
// Each wave owns 32 rows, full K in registers (af 64 VGPR). B fragments loaded
// global->register per 16-col chunk, 2-chunk ping-pong software pipeline.
// acc = mfma(wf, af): lane holds C row (m*16+l15), cols (s*16+lh*4 .. +3).
// EPI 0: bf16 store | EPI 1: GELU -> bf16 | EPI 2: proj remap + resid, f32
template<int EPI>
__global__ __launch_bounds__(256) void k_gemm_rr(
    const bf16* __restrict__ A, const bf16* __restrict__ Bw,
    const float* __restrict__ bias,
    float* __restrict__ Cf, bf16* __restrict__ Cb,
    const float* __restrict__ resid, int N)
{
  const int tid = threadIdx.x;
  const int lane = tid & 63, l15 = lane & 15, lh = lane >> 4;
  const int rowBase = (blockIdx.x * 4 + (tid >> 6)) * 32;

  // one-time A fragment load (rows rowBase+l15, rowBase+16+l15; k = kk*32+lh*8)
  bf16x8 af0[8], af1[8];
  {
    const bf16* a0 = A + (size_t)(rowBase + l15) * 256 + lh * 8;
    #pragma unroll
    for (int kk = 0; kk < 8; ++kk) {
      af0[kk] = *(const bf16x8*)(a0 + kk * 32);
      af1[kk] = *(const bf16x8*)(a0 + 4096 + kk * 32);   // +16 rows
    }
  }

  // store row addresses
  size_t rowAddr0, rowAddr1;
  #pragma unroll
  for (int m = 0; m < 2; ++m) {
    int row = rowBase + m * 16 + l15;
    size_t ra;
    if (EPI == 2) {
      int win = row >> 6, nn = row & 63;
      int b = win >> 6, ww = win & 63;
      int ry = ((ww >> 3) << 3) + (nn >> 3);
      int rx = ((ww & 7) << 3) + (nn & 7);
      int fy = (ry + 4) & 63, fx = (rx + 4) & 63;
      ra = ((size_t)(((b << 6) + fy) << 6) + fx) * 256;
    } else {
      ra = (size_t)row * N;
    }
    if (m == 0) rowAddr0 = ra; else rowAddr1 = ra;
  }

  const bf16* bp = Bw + (size_t)l15 * 256 + lh * 8;   // chunk stride = 16*256 elems

  auto compute = [&](int s, const bf16x8* W) {
    const int colb = s * 16 + lh * 4;
    const f32x4 b4 = *(const f32x4*)(bias + colb);
    f32x4 r40, r41;
    if (EPI == 2) {
      r40 = *(const f32x4*)(resid + rowAddr0 + colb);
      r41 = *(const f32x4*)(resid + rowAddr1 + colb);
    }
    f32x4 acc0 = (f32x4){0.f,0.f,0.f,0.f};
    f32x4 acc1 = (f32x4){0.f,0.f,0.f,0.f};
    #pragma unroll
    for (int kk = 0; kk < 8; ++kk) {
      acc0 = __builtin_amdgcn_mfma_f32_16x16x32_bf16(W[kk], af0[kk], acc0, 0, 0, 0);
      acc1 = __builtin_amdgcn_mfma_f32_16x16x32_bf16(W[kk], af1[kk], acc1, 0, 0, 0);
    }
    if (EPI == 0) {
      union { bf16 h[4]; uint2 u; } p0, p1;
      #pragma unroll
      for (int j = 0; j < 4; ++j) {
        p0.h[j] = __float2bfloat16(acc0[j] + b4[j]);
        p1.h[j] = __float2bfloat16(acc1[j] + b4[j]);
      }
      *(uint2*)(Cb + rowAddr0 + colb) = p0.u;
      *(uint2*)(Cb + rowAddr1 + colb) = p1.u;
    } else if (EPI == 1) {
      union { bf16 h[4]; uint2 u; } p0, p1;
      #pragma unroll
      for (int j = 0; j < 4; ++j) {
        float v = acc0[j] + b4[j];
        float w = fmaf(v * v, 0.1029434f, 2.3022083f);   // ln2-folded tanh-GELU
        float e = __builtin_amdgcn_exp2f(-v * w);
        p0.h[j] = __float2bfloat16(v * __builtin_amdgcn_rcpf(1.0f + e));
        v = acc1[j] + b4[j];
        w = fmaf(v * v, 0.1029434f, 2.3022083f);
        e = __builtin_amdgcn_exp2f(-v * w);
        p1.h[j] = __float2bfloat16(v * __builtin_amdgcn_rcpf(1.0f + e));
      }
      *(uint2*)(Cb + rowAddr0 + colb) = p0.u;
      *(uint2*)(Cb + rowAddr1 + colb) = p1.u;
    } else {
      f32x4 o0, o1;
      #pragma unroll
      for (int j = 0; j < 4; ++j) {
        o0[j] = acc0[j] + b4[j] + r40[j];
        o1[j] = acc1[j] + b4[j] + r41[j];
      }
      *(f32x4*)(Cf + rowAddr0 + colb) = o0;
      *(f32x4*)(Cf + rowAddr1 + colb) = o1;
    }
  };

  // ping-pong pipeline over N/16 chunks (NC even for all call sites)
  bf16x8 wA[8], wB[8];
  #pragma unroll
  for (int kk = 0; kk < 8; ++kk) wA[kk] = *(const bf16x8*)(bp + kk * 32);

  const int NC = N >> 4;
  for (int s = 0; s < NC; s += 2) {
    {
      const bf16* bn = bp + (size_t)(s + 1) * 4096;
      #pragma unroll
      for (int kk = 0; kk < 8; ++kk) wB[kk] = *(const bf16x8*)(bn + kk * 32);
      compute(s, wA);
    }
    {
      if (s + 2 < NC) {
        const bf16* bn = bp + (size_t)(s + 2) * 4096;
        #pragma unroll
        for (int kk = 0; kk < 8; ++kk) wA[kk] = *(const bf16x8*)(bn + kk * 32);
      }
      compute(s + 1, wB);
    }
  }
}

// ---------------- classic tiled GEMM (for MLP2, K=1024): C = A@Bw^T ----------------
// Cf[addr] += val + bias (residual already in Cf), f32
#define BM 128
#define BN 128
#define BKK 64

__global__ __launch_bounds__(256) void k_gemm_bt3(
    const bf16* __restrict__ A, const bf16* __restrict__ Bw,
    const float* __restrict__ bias, float* __restrict__ Cf,
    int M, int N, int K)
{
  __shared__ __align__(16) char lds[BM*BKK*2 + BN*BKK*2];
  char* ldsA = lds;
  char* ldsB = lds + BM*BKK*2;

  const int tid = threadIdx.x;
  const int wid = tid >> 6;
  const int lane = tid & 63;
  const int l15 = lane & 15, lh = lane >> 4;
  const int rowBase = blockIdx.y * BM;
  const int colBase = blockIdx.x * BN;
  const int wr = (wid >> 1) * 64;
  const int wc = (wid & 1) * 64;

  f32x4 acc[4][4];
  #pragma unroll
  for (int i = 0; i < 4; ++i)
    #pragma unroll
    for (int j = 0; j < 4; ++j) acc[i][j] = (f32x4){0.f,0.f,0.f,0.f};

  for (int k0 = 0; k0 < K; k0 += BKK) {
    #pragma unroll
    for (int i = 0; i < 4; ++i) {
      int chunk = i * 4 + wid;
      int off = (chunk * 64 + lane) * 16;
      int r = off >> 7, cb = off & 127;
      int csw = cb ^ ((r & 7) << 4);
      gload_lds16((const char*)(A + (size_t)(rowBase + r) * K + k0) + csw, ldsA + chunk * 1024);
      gload_lds16((const char*)(Bw + (size_t)(colBase + r) * K + k0) + csw, ldsB + chunk * 1024);
    }
    __syncthreads();
    #pragma unroll
    for (int kk = 0; kk < BKK / 32; ++kk) {
      bf16x8 af[4], bfr[4];
      int kb = kk * 64 + lh * 16;
      #pragma unroll
      for (int m = 0; m < 4; ++m) {
        int rA = wr + m * 16 + l15;
        af[m] = *(const bf16x8*)(ldsA + rA * 128 + (kb ^ ((rA & 7) << 4)));
        int rB = wc + m * 16 + l15;
        bfr[m] = *(const bf16x8*)(ldsB + rB * 128 + (kb ^ ((rB & 7) << 4)));
      }
      #pragma unroll
      for (int m = 0; m < 4; ++m)
        #pragma unroll
        for (int n = 0; n < 4; ++n)
          acc[m][n] = __builtin_amdgcn_mfma_f32_16x16x32_bf16(bfr[n], af[m], acc[m][n], 0, 0, 0);
    }
    __syncthreads();
  }

  #pragma unroll
  for (int m = 0; m < 4; ++m) {
    size_t rowAddr = (size_t)(rowBase + wr + m * 16 + l15) * N;
    #pragma unroll
    for (int n = 0; n < 4; ++n) {
      const int colb = colBase + wc + n * 16 + lh * 4;
      const f32x4 b4 = *(const f32x4*)(bias + colb);
      f32x4* p = (f32x4*)(Cf + rowAddr + colb);
      f32x4 c = *p;
      #pragma unroll
      for (int j = 0; j < 4; ++j) c[j] += acc[m][n][j] + b4[j];
      *p = c;
    }
  }
}

// ---------------- attention: 1 wave per (window, head) ----------------
__global__ __launch_bounds__(256) void k_attn(
    const bf16* __restrict__ qkv, const float* __restrict__ btab,
    bf16* __restrict__ outp)
{
  __shared__ __align__(16) char smem[71680];
  float* sb = (float*)smem;                        // 64*64 f32 bias for this head
  const int tid = threadIdx.x, wid = tid >> 6, lane = tid & 63;
  const int l15 = lane & 15, lh = lane >> 4;
  const int h = blockIdx.x >> 8;
  const int win = ((blockIdx.x & 255) << 2) + wid;
  const int tb = win << 6;
  char* plw = smem + 16384 + wid * 9216;           // P: 64 rows x 144B
  char* vtw = smem + 16384 + 36864 + wid * 4608;   // Vt: 32 rows x 144B

  for (int i = tid; i < 4096; i += 256) sb[i] = btab[(h << 12) + i];
  __syncthreads();

  bf16x8 qf[4], kf[4];
  #pragma unroll
  for (int m = 0; m < 4; ++m) {
    size_t base = (size_t)(tb + m * 16 + l15) * 768 + h * 32 + lh * 8;
    qf[m] = *(const bf16x8*)(qkv + base);
    kf[m] = *(const bf16x8*)(qkv + base + 256);
  }
  f32x4 s[4][4];
  #pragma unroll
  for (int i = 0; i < 4; ++i)
    #pragma unroll
    for (int j = 0; j < 4; ++j) {
      s[i][j] = (f32x4){0.f,0.f,0.f,0.f};
      s[i][j] = __builtin_amdgcn_mfma_f32_16x16x32_bf16(qf[i], kf[j], s[i][j], 0, 0, 0);
    }

  #pragma unroll
  for (int it = 0; it < 32; ++it) {
    int idx = it * 64 + lane;
    int m = idx >> 5, d = idx & 31;
    bf16 vv = qkv[(size_t)(tb + m) * 768 + 512 + h * 32 + d];
    *(bf16*)(vtw + d * 144 + m * 2) = vv;
  }

  int ww = win & 63, wi = ww >> 3, wj = ww & 7;
  int labm[4];
  #pragma unroll
  for (int jf = 0; jf < 4; ++jf) {
    int m = jf * 16 + l15;
    int yy = wi * 8 + (m >> 3), xx = wj * 8 + (m & 7);
    labm[jf] = (yy < 56 ? 0 : (yy < 60 ? 1 : 2)) * 3 + (xx < 56 ? 0 : (xx < 60 ? 1 : 2));
  }
  float rsum[4][4];
  const float scale = 0.17677669529663687f;  // 1/sqrt(32)
  #pragma unroll
  for (int i = 0; i < 4; ++i) {
    #pragma unroll
    for (int j = 0; j < 4; ++j) {
      int n = i * 16 + lh * 4 + j;
      int yy = wi * 8 + (n >> 3), xx = wj * 8 + (n & 7);
      int labn = (yy < 56 ? 0 : (yy < 60 ? 1 : 2)) * 3 + (xx < 56 ? 0 : (xx < 60 ? 1 : 2));
      float vals[4]; float mx = -1e30f;
      #pragma unroll
      for (int jf = 0; jf < 4; ++jf) {
        int m = jf * 16 + l15;
        float v = s[i][jf][j] * scale + sb[(n << 6) + m];
        if (labn != labm[jf]) v -= 100.0f;
        vals[jf] = v; mx = fmaxf(mx, v);
      }
      #pragma unroll
      for (int o = 1; o < 16; o <<= 1) mx = fmaxf(mx, __shfl_xor(mx, o));
      float sum = 0.0f;
      #pragma unroll
      for (int jf = 0; jf < 4; ++jf) {
        float e = __expf(vals[jf] - mx);
        sum += e;
        *(bf16*)(plw + n * 144 + (jf * 16 + l15) * 2) = __float2bfloat16(e);
      }
      #pragma unroll
      for (int o = 1; o < 16; o <<= 1) sum += __shfl_xor(sum, o);
      rsum[i][j] = sum;
    }
  }
  __syncthreads();

  f32x4 o[4][2];
  #pragma unroll
  for (int i = 0; i < 4; ++i) { o[i][0] = (f32x4){0.f,0.f,0.f,0.f}; o[i][1] = (f32x4){0.f,0.f,0.f,0.f}; }
  #pragma unroll
  for (int kk = 0; kk < 2; ++kk) {
    bf16x8 pf[4], vf[2];
    #pragma unroll
    for (int i = 0; i < 4; ++i)
      pf[i] = *(const bf16x8*)(plw + (i * 16 + l15) * 144 + kk * 64 + lh * 16);
    #pragma unroll
    for (int df = 0; df < 2; ++df)
      vf[df] = *(const bf16x8*)(vtw + (df * 16 + l15) * 144 + kk * 64 + lh * 16);
    #pragma unroll
    for (int i = 0; i < 4; ++i)
      #pragma unroll
      for (int df = 0; df < 2; ++df)
        o[i][df] = __builtin_amdgcn_mfma_f32_16x16x32_bf16(pf[i], vf[df], o[i][df], 0, 0, 0);
  }
  #pragma unroll
  for (int i = 0; i < 4; ++i)
    #pragma unroll
    for (int df = 0; df < 2; ++df)
      #pragma unroll
      for (int j = 0; j < 4; ++j) {
        int n = i * 16 + lh * 4 + j;
        int d = df * 16 + l15;
        float v = o[i][df][j] / rsum[i][j];
        outp[(size_t)(tb + n) * 256 + h * 32 + d] = __float2bfloat16(v);
      }
}

// ---------------- launch ----------------
extern "C" void kernel_launch(void* const* d_in, const int* in_sizes, int n_in,
                              void* d_out, int out_size, void* d_ws, size_t ws_size,
                              hipStream_t stream) {
  (void)in_sizes; (void)n_in; (void)out_size; (void)ws_size;
  const float* x      = (const float*)d_in[0];
  const float* ln1_s  = (const float*)d_in[1];
  const float* ln1_b  = (const float*)d_in[2];
  const float* qkv_w  = (const float*)d_in[3];
  const float* qkv_b  = (const float*)d_in[4];
  const float* proj_w = (const float*)d_in[5];
  const float* proj_b = (const float*)d_in[6];
  const float* rel_b  = (const float*)d_in[7];
  const float* ln2_s  = (const float*)d_in[8];
  const float* ln2_b  = (const float*)d_in[9];
  const float* w1     = (const float*)d_in[10];
  const float* b1     = (const float*)d_in[11];
  const float* w2     = (const float*)d_in[12];
  const float* b2     = (const float*)d_in[13];

  char* ws = (char*)d_ws;
  bf16*  wqkv  = (bf16*)(ws + 0);               // 196608 el
  bf16*  wproj = wqkv + 196608;                 // 65536 el
  bf16*  wm1   = wqkv + 262144;                 // 262144 el
  bf16*  wm2   = wqkv + 524288;                 // 262144 el
  float* btab  = (float*)(ws + 1572864);        // 32768 f32
  bf16*  hbuf  = (bf16*)(ws + 2097152);         // 65536x256 (34MB..)
  bf16*  qkvb  = (bf16*)(ws + 35651584);        // 65536x768 (34MB..134MB)
  bf16*  attnb = (bf16*)(ws + 136314880);       // 65536x256 (130MB..163MB)
  bf16*  ln2buf = hbuf;                         // reuse (h dead after QKV gemm)
  bf16*  actb  = qkvb;                          // 65536x1024 (qkv+attn dead after proj)
  float* x1    = (float*)d_out;                 // residual lives in d_out

  k_conv_weights<<<3072, 256, 0, stream>>>(qkv_w, proj_w, w1, w2, wqkv);
  k_build_btab<<<128, 256, 0, stream>>>(rel_b, btab);
  k_ln1_window<<<16384, 256, 0, stream>>>(x, ln1_s, ln1_b, hbuf);
  k_gemm_rr<0><<<512, 256, 0, stream>>>(hbuf, wqkv, qkv_b, nullptr, qkvb, nullptr, 768);
  k_attn<<<2048, 256, 0, stream>>>(qkvb, btab, attnb);
  k_gemm_rr<2><<<512, 256, 0, stream>>>(attnb, wproj, proj_b, x1, nullptr, x, 256);
  k_ln2<<<16384, 256, 0, stream>>>(x1, ln2_s, ln2_b, ln2buf);
  k_gemm_rr<1><<<512, 256, 0, stream>>>(ln2buf, wm1, b1, nullptr, actb, nullptr, 1024);
  k_gemm_bt3<<<dim3(2, 512), 256, 0, stream>>>(actb, wm2, b2, x1, 65536, 256, 1024);
}